// Round 2
// baseline (242.263 us; speedup 1.0000x reference)
//
#include <hip/hip_runtime.h>

#define N_NODES   50000
#define N_EDGES   800000
#define IN_DIM    100
#define HIDDEN    16
#define N_CLASSES 40
#define SCAN_BLK  1024   // items per scan1 block (256 thr x 4)
#define NB_SCAN   ((N_NODES + SCAN_BLK - 1) / SCAN_BLK)   // 49

// ---------------- CSR build ----------------

__global__ __launch_bounds__(256) void hist_kernel(const int* __restrict__ dst,
                                                   int* __restrict__ deg) {
    const int e = blockIdx.x * 256 + threadIdx.x;
    atomicAdd(&deg[dst[e]], 1);
}

// Per-block exclusive scan (1024 items/block); off[i] = block-local exclusive
// prefix, bsum[b] = block total.
__global__ __launch_bounds__(256) void scan1_kernel(const int* __restrict__ deg,
                                                    int* __restrict__ off,
                                                    int* __restrict__ bsum) {
    __shared__ int lds[256];
    const int t = threadIdx.x;
    const int base = blockIdx.x * SCAN_BLK + t * 4;
    int v[4], s = 0;
#pragma unroll
    for (int q = 0; q < 4; ++q) {
        const int i = base + q;
        v[q] = (i < N_NODES) ? deg[i] : 0;
        s += v[q];
    }
    lds[t] = s;
    __syncthreads();
    int inc = s;
    for (int ofs = 1; ofs < 256; ofs <<= 1) {
        const int y = (t >= ofs) ? lds[t - ofs] : 0;
        __syncthreads();
        inc += y;
        lds[t] = inc;
        __syncthreads();
    }
    int run = inc - s;  // exclusive prefix of this thread's 4 items
#pragma unroll
    for (int q = 0; q < 4; ++q) {
        const int i = base + q;
        if (i < N_NODES) off[i] = run;
        run += v[q];
    }
    if (t == 255) bsum[blockIdx.x] = inc;
}

// Scan the NB_SCAN block totals in place (exclusive).
__global__ __launch_bounds__(64) void scan2_kernel(int* __restrict__ bsum) {
    __shared__ int lds[64];
    const int t = threadIdx.x;
    const int s = (t < NB_SCAN) ? bsum[t] : 0;
    lds[t] = s;
    __syncthreads();
    int inc = s;
    for (int ofs = 1; ofs < 64; ofs <<= 1) {
        const int y = (t >= ofs) ? lds[t - ofs] : 0;
        __syncthreads();
        inc += y;
        lds[t] = inc;
        __syncthreads();
    }
    if (t < NB_SCAN) bsum[t] = inc - s;
}

// Globalize offsets; duplicate into cursor for the scatter pass.
__global__ __launch_bounds__(256) void scan3_kernel(int* __restrict__ off,
                                                    int* __restrict__ cursor,
                                                    const int* __restrict__ bsum) {
    const int i = blockIdx.x * 256 + threadIdx.x;
    if (i >= N_NODES) return;
    const int o = off[i] + bsum[i >> 10];
    off[i] = o;
    cursor[i] = o;
}

__global__ __launch_bounds__(256) void scatter_kernel(const int* __restrict__ src,
                                                      const int* __restrict__ dst,
                                                      const float* __restrict__ val,
                                                      int* __restrict__ cursor,
                                                      int2* __restrict__ csr) {
    const int e = blockIdx.x * 256 + threadIdx.x;
    const int d = dst[e];
    const int pos = atomicAdd(&cursor[d], 1);
    csr[pos] = make_int2(src[e], __float_as_int(val[e]));
}

// ---------------- compute ----------------

// y1 = X @ W1   [N,100] @ [100,16] -> [N,16]; float4 LDS reads both operands.
__global__ __launch_bounds__(256) void gemm_xw1(const float* __restrict__ X,
                                                const float* __restrict__ W,
                                                float* __restrict__ Y) {
    __shared__ __align__(16) float sX[16 * IN_DIM];   // 6.4 KB, row-major
    __shared__ __align__(16) float sWt[HIDDEN * IN_DIM]; // W1 transposed [16][100]
    const int tid  = threadIdx.x;
    const int row0 = blockIdx.x * 16;

    for (int i = tid; i < IN_DIM * HIDDEN; i += 256) {
        const int k = i >> 4, j = i & 15;            // W[k][j]
        sWt[j * IN_DIM + k] = W[i];
    }
    const float* xbase = X + (size_t)row0 * IN_DIM;
    for (int i = tid; i < 16 * IN_DIM; i += 256) sX[i] = xbase[i];
    __syncthreads();

    const int r = tid >> 4, j = tid & 15;
    const float4* ax = (const float4*)&sX[r * IN_DIM];
    const float4* bw = (const float4*)&sWt[j * IN_DIM];
    float acc = 0.f;
#pragma unroll
    for (int q = 0; q < IN_DIM / 4; ++q) {
        const float4 a = ax[q];
        const float4 b = bw[q];
        acc = fmaf(a.x, b.x, acc);
        acc = fmaf(a.y, b.y, acc);
        acc = fmaf(a.z, b.z, acc);
        acc = fmaf(a.w, b.w, acc);
    }
    Y[(size_t)(row0 + r) * HIDDEN + j] = acc;
}

// Z[n][j] = sum over n's in-edges of val * (relu?) X[src][j]. Gather, no atomics.
template <bool RELU>
__global__ __launch_bounds__(256) void spmm_gather(const int* __restrict__ off,
                                                   const int* __restrict__ deg,
                                                   const int2* __restrict__ csr,
                                                   const float* __restrict__ X,
                                                   float* __restrict__ Z) {
    const int tid = blockIdx.x * 256 + threadIdx.x;
    const int n = tid >> 4, j = tid & 15;
    const int o = off[n], c = deg[n];
    const int2* ep = csr + o;
    float acc = 0.f;
    for (int i = 0; i < c; ++i) {
        const int2 e = ep[i];
        float x = X[(size_t)e.x * HIDDEN + j];
        if (RELU) x = fmaxf(x, 0.f);
        acc = fmaf(__int_as_float(e.y), x, acc);
    }
    Z[(size_t)n * HIDDEN + j] = acc;
}

// out[n] = log_softmax(Z[n] @ W2)
__global__ __launch_bounds__(256) void out_logsoftmax(const float* __restrict__ Z,
                                                      const float* __restrict__ W2,
                                                      float* __restrict__ out) {
    __shared__ float sW[HIDDEN * N_CLASSES];
    const int tid = threadIdx.x;
    for (int i = tid; i < HIDDEN * N_CLASSES; i += 256) sW[i] = W2[i];
    __syncthreads();

    const int n = blockIdx.x * 256 + tid;
    if (n >= N_NODES) return;

    float z[HIDDEN];
    const float4* zp = (const float4*)(Z + (size_t)n * HIDDEN);
#pragma unroll
    for (int q = 0; q < 4; ++q) {
        const float4 t = zp[q];
        z[q * 4 + 0] = t.x; z[q * 4 + 1] = t.y;
        z[q * 4 + 2] = t.z; z[q * 4 + 3] = t.w;
    }

    float o[N_CLASSES];
#pragma unroll
    for (int c = 0; c < N_CLASSES; ++c) {
        float acc = 0.f;
#pragma unroll
        for (int k = 0; k < HIDDEN; ++k)
            acc = fmaf(z[k], sW[k * N_CLASSES + c], acc);
        o[c] = acc;
    }

    float m = -INFINITY;
#pragma unroll
    for (int c = 0; c < N_CLASSES; ++c) m = fmaxf(m, o[c]);
    float s = 0.f;
#pragma unroll
    for (int c = 0; c < N_CLASSES; ++c) s += __expf(o[c] - m);
    const float lse = m + __logf(s);

    float* op = out + (size_t)n * N_CLASSES;
#pragma unroll
    for (int c = 0; c < N_CLASSES; ++c) op[c] = o[c] - lse;
}

extern "C" void kernel_launch(void* const* d_in, const int* in_sizes, int n_in,
                              void* d_out, int out_size, void* d_ws, size_t ws_size,
                              hipStream_t stream) {
    const float* features = (const float*)d_in[0];  // [50000,100]
    const int*   edge_src = (const int*)d_in[1];    // [800000]
    const int*   edge_dst = (const int*)d_in[2];    // [800000]
    const float* edge_val = (const float*)d_in[3];  // [800000]
    const float* W1       = (const float*)d_in[4];  // [100,16]
    const float* W2       = (const float*)d_in[5];  // [16,40]
    float*       out      = (float*)d_out;          // [50000,40]

    // workspace layout (8B-aligned csr first)
    char* ws = (char*)d_ws;
    int2*  csr    = (int2*)ws;                       ws += (size_t)N_EDGES * sizeof(int2);
    float* bufY   = (float*)ws;                      ws += (size_t)N_NODES * HIDDEN * sizeof(float);
    float* z1     = (float*)ws;                      ws += (size_t)N_NODES * HIDDEN * sizeof(float);
    int*   deg    = (int*)ws;                        ws += (size_t)N_NODES * sizeof(int);
    int*   off    = (int*)ws;                        ws += (size_t)N_NODES * sizeof(int);
    int*   cursor = (int*)ws;                        ws += (size_t)N_NODES * sizeof(int);
    int*   bsum   = (int*)ws;                        ws += 64 * sizeof(int);

    // --- CSR build (amortized over both SpMMs) ---
    hipMemsetAsync(deg, 0, (size_t)N_NODES * sizeof(int), stream);
    hist_kernel<<<N_EDGES / 256, 256, 0, stream>>>(edge_dst, deg);
    scan1_kernel<<<NB_SCAN, 256, 0, stream>>>(deg, off, bsum);
    scan2_kernel<<<1, 64, 0, stream>>>(bsum);
    scan3_kernel<<<(N_NODES + 255) / 256, 256, 0, stream>>>(off, cursor, bsum);
    scatter_kernel<<<N_EDGES / 256, 256, 0, stream>>>(edge_src, edge_dst, edge_val,
                                                      cursor, csr);

    // --- y1 = X @ W1 ---
    gemm_xw1<<<N_NODES / 16, 256, 0, stream>>>(features, W1, bufY);

    // --- z1 = A @ y1 ; z2 = A @ relu(z1) (z2 reuses bufY) ---
    spmm_gather<false><<<(N_NODES * HIDDEN) / 256, 256, 0, stream>>>(off, deg, csr, bufY, z1);
    spmm_gather<true><<<(N_NODES * HIDDEN) / 256, 256, 0, stream>>>(off, deg, csr, z1, bufY);

    // --- out = log_softmax(z2 @ W2) ---
    out_logsoftmax<<<(N_NODES + 255) / 256, 256, 0, stream>>>(bufY, W2, out);
}